// Round 7
// baseline (209.917 us; speedup 1.0000x reference)
//
#include <hip/hip_runtime.h>
#include <hip/hip_bf16.h>
#include <stdint.h>

#define BB 2
#define CC 256
#define HH 96
#define WW 320
#define NPIX 16384
#define NLAY 5
#define KDIM 1280   // CC*NLAY
#define NDIM 32768  // BB*NPIX
#define NKT (KDIM / 32)   // 40 K-tiles

typedef float f32x4 __attribute__((ext_vector_type(4)));
typedef float f32x2 __attribute__((ext_vector_type(2)));
typedef __bf16 bf16x8 __attribute__((ext_vector_type(8)));
typedef __bf16 bf16x4 __attribute__((ext_vector_type(4)));

// ---------- K1: cumsum along W + transpose (B,C,H,W) -> (B,H,W,C) ----------
__global__ __launch_bounds__(1024) void k1_cumw(const float* __restrict__ feat,
                                                float* __restrict__ integ) {
  __shared__ float tile[WW * 17];
  const int t = threadIdx.x;
  const int wave = t >> 6;
  const int lane = t & 63;
  const int blk = blockIdx.x;           // (b, h, cg)
  const int cg = blk & 15;
  const int h = (blk >> 4) % HH;
  const int b = blk / (16 * HH);
  const int c = cg * 16 + wave;
  const float* src = feat + (size_t)((b * CC + c) * HH + h) * WW;

  float carry = 0.f;
#pragma unroll
  for (int chunk = 0; chunk < 5; ++chunk) {
    float v = src[chunk * 64 + lane];
#pragma unroll
    for (int d = 1; d < 64; d <<= 1) {
      float u = __shfl_up(v, d, 64);
      if (lane >= d) v += u;
    }
    v += carry;
    carry = __shfl(v, 63, 64);
    tile[(chunk * 64 + lane) * 17 + wave] = v;
  }
  __syncthreads();
  float* dst = integ + (size_t)((b * HH + h) * WW) * CC + cg * 16;
#pragma unroll
  for (int g = 0; g < 5; ++g) {
    int idx = g * 1024 + t;             // 0..5119
    int w = idx >> 4;
    int cw = idx & 15;
    dst[(size_t)w * CC + cw] = tile[w * 17 + cw];
  }
}

// ---------- K2: cumsum along H, in place on (B,H,W,C) ----------
// Wave per (b, w, c-half): lane owns f32x2 (8B) -> 512B per load instr; 1280
// single-wave blocks = 5 waves/CU; unroll gives multiple h-steps in flight.
__global__ __launch_bounds__(64) void k2_cumh(float* __restrict__ integ) {
  const int blk = blockIdx.x;            // (b, w, half)
  const int half = blk & 1;
  const int w = (blk >> 1) % WW;
  const int b = blk / (2 * WW);
  float* base = integ + ((size_t)(b * HH) * WW + w) * CC + half * 128 + threadIdx.x * 2;
  const size_t stride = (size_t)WW * CC;
  f32x2 run = {0.f, 0.f};
#pragma unroll 6
  for (int h = 0; h < HH; ++h) {
    f32x2* p = (f32x2*)(base + (size_t)h * stride);
    f32x2 v = *p;
    run += v;
    *p = run;
  }
}

// ---------- K3+K5 fused: box geometry (640 blocks) + Wc repack (1280 blocks) --
// NB: keep geometry SEPARATE from k4 — fusing into k4 makes all 64 lanes
// redundantly compute 16 fp32 divides per box (R3: k4 57->173us, VALUBusy 93%).
__global__ __launch_bounds__(256) void k3k5(const float* __restrict__ grid,
                                            const float* __restrict__ calib,
                                            const float* __restrict__ Wc,
                                            float4* __restrict__ coords,
                                            float* __restrict__ scales,
                                            __bf16* __restrict__ Wbf) {
  const int bid = blockIdx.x;
  if (bid >= 640) {                     // ---- K5 part: repack Wc -> bf16 ----
    int o = (bid - 640) * 256 + threadIdx.x;   // co*1280 + n*256 + c
    int co = o / KDIM;
    int kk = o % KDIM;
    int n = kk >> 8;
    int c = kk & 255;
    Wbf[o] = (__bf16)Wc[co * KDIM + c * NLAY + n];
    return;
  }
  // ---- K3 part: one thread per box ----
  int box = bid * 256 + threadIdx.x;    // ((b*5+n)<<14) | pix
  int pix = box & (NPIX - 1);
  int bn = box >> 14;
  int n = bn % NLAY;
  int b = bn / NLAY;
  const float* cb = calib + b * 12;
  float c00 = cb[0], c01 = cb[1], c02 = cb[2], c03 = cb[3];
  float c10 = cb[4], c11 = cb[5], c12 = cb[6], c13 = cb[7];
  float c20 = cb[8], c21 = cb[9], c22 = cb[10], c23 = cb[11];
  float gx = grid[pix * 3 + 0], gy = grid[pix * 3 + 1], gz = grid[pix * 3 + 2];
  float zoff = 32.0f * (float)n;
  const float ox[8] = {-12.5f, 12.5f, 12.5f, -12.5f, -12.5f, 12.5f, 12.5f, -12.5f};
  const float oy[8] = {-12.5f, -12.5f, 12.5f, 12.5f, -12.5f, -12.5f, 12.5f, 12.5f};
  float xmn = 1e30f, ymn = 1e30f, xmx = -1e30f, ymx = -1e30f;
#pragma unroll
  for (int k = 0; k < 8; ++k) {
    float X = gx + ox[k];
    float Y = gy + oy[k];
    float Z = gz + zoff + ((k >= 4) ? 32.0f : 0.0f);
    float px = c00 * X + c01 * Y + c02 * Z + c03;
    float py = c10 * X + c11 * Y + c12 * Z + c13;
    float pz = c20 * X + c21 * Y + c22 * Z + c23;
    float d = fmaxf(pz, 1e-6f);
    float nx = fminf(fmaxf(2.0f * (px / d) / 320.0f - 1.0f, -1.0f), 0.95f);
    float ny = fminf(fmaxf(2.0f * (py / d) / 96.0f - 1.0f, -1.0f), 0.95f);
    xmn = fminf(xmn, nx); xmx = fmaxf(xmx, nx);
    ymn = fminf(ymn, ny); ymx = fmaxf(ymx, ny);
  }
  float dx = xmx - xmn, dy = ymx - ymn;
  float area = (dx * dy) * 30720.0f + 1e-6f;
  bool vis = (area > 1e-6f) && (area < 9216.0f);
  float X0 = ((xmn + 1.0f) * 320.0f - 1.0f) * 0.5f;
  float Y0 = ((ymn + 1.0f) * 96.0f - 1.0f) * 0.5f;
  float X1 = ((xmx + 1.0f) * 320.0f - 1.0f) * 0.5f;
  float Y1 = ((ymx + 1.0f) * 96.0f - 1.0f) * 0.5f;
  coords[box] = make_float4(X0, Y0, X1, Y1);
  scales[box] = vis ? 1.0f / area : 0.0f;
}

// ---------- K4: box-filtered features -> vox (bf16), K permuted to n*256+c ----------
__global__ __launch_bounds__(256) void k4_vox(const float* __restrict__ integ,
                                              const float4* __restrict__ coords,
                                              const float* __restrict__ scales,
                                              __bf16* __restrict__ voxA) {
  const int wave = threadIdx.x >> 6;
  const int lane = threadIdx.x & 63;
  const int box = blockIdx.x * 4 + wave;
  const int pix = box & (NPIX - 1);
  const int bn = box >> 14;
  const int n = bn % NLAY;
  const int b = bn / NLAY;
  const size_t row = (size_t)(b * NPIX + pix);
  bf16x4* dst = (bf16x4*)(voxA + row * KDIM + n * CC + lane * 4);
  const float scale = scales[box];
  if (scale == 0.f) {                 // wave-uniform branch
    *dst = bf16x4{(__bf16)0.f, (__bf16)0.f, (__bf16)0.f, (__bf16)0.f};
    return;
  }
  const float4 q = coords[box];

  float xw[4]; int xi[4];
  float yw[4]; int yi[4];
  {
    float f0 = floorf(q.x); int i0 = (int)f0; float w1 = q.x - f0;
    xw[0] = (i0 >= 0 && i0 < WW) ? (1.f - w1) : 0.f;
    xw[1] = (i0 + 1 < WW) ? w1 : 0.f;
    xi[0] = min(max(i0, 0), WW - 1); xi[1] = min(max(i0 + 1, 0), WW - 1);
    float f1 = floorf(q.z); int i1 = (int)f1; float v1 = q.z - f1;
    xw[2] = (i1 >= 0 && i1 < WW) ? -(1.f - v1) : 0.f;
    xw[3] = (i1 + 1 < WW) ? -v1 : 0.f;
    xi[2] = min(max(i1, 0), WW - 1); xi[3] = min(max(i1 + 1, 0), WW - 1);
  }
  {
    float f0 = floorf(q.y); int j0 = (int)f0; float w1 = q.y - f0;
    yw[0] = (j0 >= 0 && j0 < HH) ? (1.f - w1) : 0.f;
    yw[1] = (j0 + 1 < HH) ? w1 : 0.f;
    yi[0] = min(max(j0, 0), HH - 1); yi[1] = min(max(j0 + 1, 0), HH - 1);
    float f1 = floorf(q.w); int j1 = (int)f1; float v1 = q.w - f1;
    yw[2] = (j1 >= 0 && j1 < HH) ? -(1.f - v1) : 0.f;
    yw[3] = (j1 + 1 < HH) ? -v1 : 0.f;
    yi[2] = min(max(j1, 0), HH - 1); yi[3] = min(max(j1 + 1, 0), HH - 1);
  }
  const float* base = integ + (size_t)(b * HH) * WW * CC + lane * 4;
  f32x4 val = {0.f, 0.f, 0.f, 0.f};
#pragma unroll
  for (int jj = 0; jj < 4; ++jj) {
    if (yw[jj] == 0.f) continue;          // wave-uniform branch
    const float* rp = base + (size_t)yi[jj] * WW * CC;
    f32x4 rs = {0.f, 0.f, 0.f, 0.f};
#pragma unroll
    for (int ii = 0; ii < 4; ++ii) {
      if (xw[ii] != 0.f) {
        f32x4 v = *(const f32x4*)(rp + (size_t)xi[ii] * CC);
        rs += xw[ii] * v;
      }
    }
    val += yw[jj] * rs;
  }
  val *= scale;
  *dst = bf16x4{(__bf16)val.x, (__bf16)val.y, (__bf16)val.z, (__bf16)val.w};
}

// ---------- async 16B global -> LDS ----------
__device__ __forceinline__ void glds16(const void* g, void* l) {
  __builtin_amdgcn_global_load_lds(
      (const __attribute__((address_space(1))) void*)g,
      (__attribute__((address_space(3))) void*)(uint32_t)(uintptr_t)l,
      16, 0, 0);
}

// ---------- K6: GEMM  C[co, r] = sum_k Wbf[co,k] * vox[r,k]; +bias, relu ----------
// M=256 (co, FULL per block), N=32768, K=1280. Grid = 256 N-tiles of 128 ->
// vox (84MB) fetched from HBM exactly ONCE (old grid=(2,256) fetched it twice:
// the 2 M-blocks per N-tile land on different XCDs -> both miss L2). A (0.64MB)
// is L2-resident. HBM floor ~120MB ≈ 19us vs old ~200MB. Per wave: 128m x 64n
// = 8x4 f32x4 acc (~176 VGPR, fits 256). 3-buffer LDS ring (72KB), depth-2
// glds prefetch, wait vmcnt(6) mid-loop. Buf (kt+2)%3 == buf (kt-1)%3, whose
// LDS reads completed before barrier kt -> safe. XOR swizzle on GLOBAL chunk.
__global__ __launch_bounds__(256) void k6_gemm(const __bf16* __restrict__ A,   // 256 x 1280
                                               const __bf16* __restrict__ Bm,  // 32768 x 1280
                                               const float* __restrict__ bias,
                                               float* __restrict__ out) {
  __shared__ __align__(16) __bf16 As[3][256 * 32];
  __shared__ __align__(16) __bf16 Bs[3][128 * 32];
  const int tileN = blockIdx.x * 128;
  const int tid = threadIdx.x;
  const int lane = tid & 63;
  const int wave = tid >> 6;
  const int wm = (wave >> 1) * 128;   // waves: 2 (m) x 2 (n)
  const int wn = (wave & 1) * 64;

  f32x4 acc[8][4];
#pragma unroll
  for (int i = 0; i < 8; ++i)
#pragma unroll
    for (int j = 0; j < 4; ++j)
      acc[i][j] = f32x4{0.f, 0.f, 0.f, 0.f};

  const int r16 = lane & 15;
  const int q4 = lane >> 4;        // 0..3 -> k-chunk
  const int srow = lane >> 2;      // staging row within 16-row group
  const int sch = lane & 3;        // staging 8-elem chunk

  auto stage = [&](int buf, int kt) {
    const int k0 = kt * 32;
#pragma unroll
    for (int rr = 0; rr < 4; ++rr) {          // A: 256 rows
      const int base_row = wave * 16 + rr * 64;
      const int row = base_row + srow;
      const int gch = sch ^ (row & 3);
      glds16(A + (size_t)row * KDIM + k0 + gch * 8,
             (void*)(&As[buf][base_row * 32] + lane * 8));
    }
#pragma unroll
    for (int rr = 0; rr < 2; ++rr) {          // B: 128 rows
      const int base_row = wave * 16 + rr * 64;
      const int row = base_row + srow;
      const int gch = sch ^ (row & 3);
      glds16(Bm + (size_t)(tileN + row) * KDIM + k0 + gch * 8,
             (void*)(&Bs[buf][base_row * 32] + lane * 8));
    }
  };

  stage(0, 0);
  stage(1, 1);
  for (int kt = 0; kt < NKT; ++kt) {
    const int cur = kt % 3;
    // 6 glds per stage; mid-loop: one stage (6) still in flight after wait.
    if (kt < NKT - 1) __builtin_amdgcn_s_waitcnt(0xF76);  // vmcnt(6)
    else              __builtin_amdgcn_s_waitcnt(0xF70);  // vmcnt(0)
    __builtin_amdgcn_s_barrier();
    if (kt + 2 < NKT) stage((kt + 2) % 3, kt + 2);
    bf16x8 af[8], bg[4];
#pragma unroll
    for (int i = 0; i < 8; ++i) {
      int m = wm + i * 16 + r16;
      af[i] = *(const bf16x8*)(&As[cur][m * 32] + (q4 ^ (m & 3)) * 8);
    }
#pragma unroll
    for (int j = 0; j < 4; ++j) {
      int nr = wn + j * 16 + r16;
      bg[j] = *(const bf16x8*)(&Bs[cur][nr * 32] + (q4 ^ (nr & 3)) * 8);
    }
#pragma unroll
    for (int i = 0; i < 8; ++i)
#pragma unroll
      for (int j = 0; j < 4; ++j)
        acc[i][j] = __builtin_amdgcn_mfma_f32_16x16x32_bf16(af[i], bg[j], acc[i][j], 0, 0, 0);
  }

#pragma unroll
  for (int i = 0; i < 8; ++i) {
#pragma unroll
    for (int j = 0; j < 4; ++j) {
      int nn = tileN + wn + j * 16 + r16;
      int bI = nn >> 14;
      int pix = nn & (NPIX - 1);
#pragma unroll
      for (int r = 0; r < 4; ++r) {
        int co = wm + i * 16 + q4 * 4 + r;
        float v = acc[i][j][r] + bias[co];
        out[(size_t)(bI * CC + co) * NPIX + pix] = fmaxf(v, 0.f);
      }
    }
  }
}

extern "C" void kernel_launch(void* const* d_in, const int* in_sizes, int n_in,
                              void* d_out, int out_size, void* d_ws, size_t ws_size,
                              hipStream_t stream) {
  const float* feat  = (const float*)d_in[0];
  const float* calib = (const float*)d_in[1];
  const float* grid  = (const float*)d_in[2];
  const float* Wc    = (const float*)d_in[3];
  const float* bc    = (const float*)d_in[4];
  float* out = (float*)d_out;

  char* ws = (char*)d_ws;
  const size_t SZ_INTEG = (size_t)BB * HH * WW * CC * 4;   // 62,914,560
  const size_t SZ_VOX   = (size_t)NDIM * KDIM * 2;         // 83,886,080
  const size_t SZ_WBF   = (size_t)CC * KDIM * 2;           //    655,360
  const size_t SZ_CRD   = (size_t)BB * NLAY * NPIX * 16;   //  2,621,440
  const size_t SZ_SCL   = (size_t)BB * NLAY * NPIX * 4;    //    655,360
  if (ws_size < SZ_INTEG + SZ_VOX + SZ_WBF + SZ_CRD + SZ_SCL) return;

  float*  integ  = (float*)ws;
  __bf16* voxA   = (__bf16*)(ws + SZ_INTEG);
  __bf16* Wbf    = (__bf16*)(ws + SZ_INTEG + SZ_VOX);
  float4* coords = (float4*)(ws + SZ_INTEG + SZ_VOX + SZ_WBF);
  float*  scales = (float*)(ws + SZ_INTEG + SZ_VOX + SZ_WBF + SZ_CRD);

  k1_cumw<<<dim3(BB * HH * 16), dim3(1024), 0, stream>>>(feat, integ);
  k2_cumh<<<dim3(BB * WW * 2), dim3(64), 0, stream>>>(integ);
  k3k5<<<dim3(640 + 1280), dim3(256), 0, stream>>>(grid, calib, Wc, coords, scales, Wbf);
  k4_vox<<<dim3(BB * NLAY * NPIX / 4), dim3(256), 0, stream>>>(integ, coords, scales, voxA);
  k6_gemm<<<dim3(NDIM / 128), dim3(256), 0, stream>>>(Wbf, voxA, bc, out);
}

// Round 8
// 201.867 us; speedup vs baseline: 1.0399x; 1.0399x over previous
//
#include <hip/hip_runtime.h>
#include <hip/hip_bf16.h>
#include <stdint.h>

#define BB 2
#define CC 256
#define HH 96
#define WW 320
#define NPIX 16384
#define NLAY 5
#define KDIM 1280   // CC*NLAY
#define NDIM 32768  // BB*NPIX
#define NKT (KDIM / 32)   // 40 K-tiles

typedef float f32x4 __attribute__((ext_vector_type(4)));
typedef float f32x2 __attribute__((ext_vector_type(2)));
typedef __bf16 bf16x8 __attribute__((ext_vector_type(8)));
typedef __bf16 bf16x4 __attribute__((ext_vector_type(4)));

// ---------- K1: cumsum along W + transpose (B,C,H,W) -> (B,H,W,C) ----------
__global__ __launch_bounds__(1024) void k1_cumw(const float* __restrict__ feat,
                                                float* __restrict__ integ) {
  __shared__ float tile[WW * 17];
  const int t = threadIdx.x;
  const int wave = t >> 6;
  const int lane = t & 63;
  const int blk = blockIdx.x;           // (b, h, cg)
  const int cg = blk & 15;
  const int h = (blk >> 4) % HH;
  const int b = blk / (16 * HH);
  const int c = cg * 16 + wave;
  const float* src = feat + (size_t)((b * CC + c) * HH + h) * WW;

  float carry = 0.f;
#pragma unroll
  for (int chunk = 0; chunk < 5; ++chunk) {
    float v = src[chunk * 64 + lane];
#pragma unroll
    for (int d = 1; d < 64; d <<= 1) {
      float u = __shfl_up(v, d, 64);
      if (lane >= d) v += u;
    }
    v += carry;
    carry = __shfl(v, 63, 64);
    tile[(chunk * 64 + lane) * 17 + wave] = v;
  }
  __syncthreads();
  float* dst = integ + (size_t)((b * HH + h) * WW) * CC + cg * 16;
#pragma unroll
  for (int g = 0; g < 5; ++g) {
    int idx = g * 1024 + t;             // 0..5119
    int w = idx >> 4;
    int cw = idx & 15;
    dst[(size_t)w * CC + cw] = tile[w * 17 + cw];
  }
}

// ---------- K2: cumsum along H, in place on (B,H,W,C) ----------
// Wave per (b, w, c-half): lane owns f32x2 (8B) -> 512B per load instr; 1280
// single-wave blocks = 5 waves/CU; unroll gives multiple h-steps in flight.
__global__ __launch_bounds__(64) void k2_cumh(float* __restrict__ integ) {
  const int blk = blockIdx.x;            // (b, w, half)
  const int half = blk & 1;
  const int w = (blk >> 1) % WW;
  const int b = blk / (2 * WW);
  float* base = integ + ((size_t)(b * HH) * WW + w) * CC + half * 128 + threadIdx.x * 2;
  const size_t stride = (size_t)WW * CC;
  f32x2 run = {0.f, 0.f};
#pragma unroll 6
  for (int h = 0; h < HH; ++h) {
    f32x2* p = (f32x2*)(base + (size_t)h * stride);
    f32x2 v = *p;
    run += v;
    *p = run;
  }
}

// ---------- K3+K5 fused: box geometry (640 blocks) + Wc repack (1280 blocks) --
// NB: keep geometry SEPARATE from k4 — fusing into k4 makes all 64 lanes
// redundantly compute 16 fp32 divides per box (R3: k4 57->173us, VALUBusy 93%).
__global__ __launch_bounds__(256) void k3k5(const float* __restrict__ grid,
                                            const float* __restrict__ calib,
                                            const float* __restrict__ Wc,
                                            float4* __restrict__ coords,
                                            float* __restrict__ scales,
                                            __bf16* __restrict__ Wbf) {
  const int bid = blockIdx.x;
  if (bid >= 640) {                     // ---- K5 part: repack Wc -> bf16 ----
    int o = (bid - 640) * 256 + threadIdx.x;   // co*1280 + n*256 + c
    int co = o / KDIM;
    int kk = o % KDIM;
    int n = kk >> 8;
    int c = kk & 255;
    Wbf[o] = (__bf16)Wc[co * KDIM + c * NLAY + n];
    return;
  }
  // ---- K3 part: one thread per box ----
  int box = bid * 256 + threadIdx.x;    // ((b*5+n)<<14) | pix
  int pix = box & (NPIX - 1);
  int bn = box >> 14;
  int n = bn % NLAY;
  int b = bn / NLAY;
  const float* cb = calib + b * 12;
  float c00 = cb[0], c01 = cb[1], c02 = cb[2], c03 = cb[3];
  float c10 = cb[4], c11 = cb[5], c12 = cb[6], c13 = cb[7];
  float c20 = cb[8], c21 = cb[9], c22 = cb[10], c23 = cb[11];
  float gx = grid[pix * 3 + 0], gy = grid[pix * 3 + 1], gz = grid[pix * 3 + 2];
  float zoff = 32.0f * (float)n;
  const float ox[8] = {-12.5f, 12.5f, 12.5f, -12.5f, -12.5f, 12.5f, 12.5f, -12.5f};
  const float oy[8] = {-12.5f, -12.5f, 12.5f, 12.5f, -12.5f, -12.5f, 12.5f, 12.5f};
  float xmn = 1e30f, ymn = 1e30f, xmx = -1e30f, ymx = -1e30f;
#pragma unroll
  for (int k = 0; k < 8; ++k) {
    float X = gx + ox[k];
    float Y = gy + oy[k];
    float Z = gz + zoff + ((k >= 4) ? 32.0f : 0.0f);
    float px = c00 * X + c01 * Y + c02 * Z + c03;
    float py = c10 * X + c11 * Y + c12 * Z + c13;
    float pz = c20 * X + c21 * Y + c22 * Z + c23;
    float d = fmaxf(pz, 1e-6f);
    float nx = fminf(fmaxf(2.0f * (px / d) / 320.0f - 1.0f, -1.0f), 0.95f);
    float ny = fminf(fmaxf(2.0f * (py / d) / 96.0f - 1.0f, -1.0f), 0.95f);
    xmn = fminf(xmn, nx); xmx = fmaxf(xmx, nx);
    ymn = fminf(ymn, ny); ymx = fmaxf(ymx, ny);
  }
  float dx = xmx - xmn, dy = ymx - ymn;
  float area = (dx * dy) * 30720.0f + 1e-6f;
  bool vis = (area > 1e-6f) && (area < 9216.0f);
  float X0 = ((xmn + 1.0f) * 320.0f - 1.0f) * 0.5f;
  float Y0 = ((ymn + 1.0f) * 96.0f - 1.0f) * 0.5f;
  float X1 = ((xmx + 1.0f) * 320.0f - 1.0f) * 0.5f;
  float Y1 = ((ymx + 1.0f) * 96.0f - 1.0f) * 0.5f;
  coords[box] = make_float4(X0, Y0, X1, Y1);
  scales[box] = vis ? 1.0f / area : 0.0f;
}

// ---------- K4: box-filtered features -> vox (bf16), K permuted to n*256+c ----------
__global__ __launch_bounds__(256) void k4_vox(const float* __restrict__ integ,
                                              const float4* __restrict__ coords,
                                              const float* __restrict__ scales,
                                              __bf16* __restrict__ voxA) {
  const int wave = threadIdx.x >> 6;
  const int lane = threadIdx.x & 63;
  const int box = blockIdx.x * 4 + wave;
  const int pix = box & (NPIX - 1);
  const int bn = box >> 14;
  const int n = bn % NLAY;
  const int b = bn / NLAY;
  const size_t row = (size_t)(b * NPIX + pix);
  bf16x4* dst = (bf16x4*)(voxA + row * KDIM + n * CC + lane * 4);
  const float scale = scales[box];
  if (scale == 0.f) {                 // wave-uniform branch
    *dst = bf16x4{(__bf16)0.f, (__bf16)0.f, (__bf16)0.f, (__bf16)0.f};
    return;
  }
  const float4 q = coords[box];

  float xw[4]; int xi[4];
  float yw[4]; int yi[4];
  {
    float f0 = floorf(q.x); int i0 = (int)f0; float w1 = q.x - f0;
    xw[0] = (i0 >= 0 && i0 < WW) ? (1.f - w1) : 0.f;
    xw[1] = (i0 + 1 < WW) ? w1 : 0.f;
    xi[0] = min(max(i0, 0), WW - 1); xi[1] = min(max(i0 + 1, 0), WW - 1);
    float f1 = floorf(q.z); int i1 = (int)f1; float v1 = q.z - f1;
    xw[2] = (i1 >= 0 && i1 < WW) ? -(1.f - v1) : 0.f;
    xw[3] = (i1 + 1 < WW) ? -v1 : 0.f;
    xi[2] = min(max(i1, 0), WW - 1); xi[3] = min(max(i1 + 1, 0), WW - 1);
  }
  {
    float f0 = floorf(q.y); int j0 = (int)f0; float w1 = q.y - f0;
    yw[0] = (j0 >= 0 && j0 < HH) ? (1.f - w1) : 0.f;
    yw[1] = (j0 + 1 < HH) ? w1 : 0.f;
    yi[0] = min(max(j0, 0), HH - 1); yi[1] = min(max(j0 + 1, 0), HH - 1);
    float f1 = floorf(q.w); int j1 = (int)f1; float v1 = q.w - f1;
    yw[2] = (j1 >= 0 && j1 < HH) ? -(1.f - v1) : 0.f;
    yw[3] = (j1 + 1 < HH) ? -v1 : 0.f;
    yi[2] = min(max(j1, 0), HH - 1); yi[3] = min(max(j1 + 1, 0), HH - 1);
  }
  const float* base = integ + (size_t)(b * HH) * WW * CC + lane * 4;
  f32x4 val = {0.f, 0.f, 0.f, 0.f};
#pragma unroll
  for (int jj = 0; jj < 4; ++jj) {
    if (yw[jj] == 0.f) continue;          // wave-uniform branch
    const float* rp = base + (size_t)yi[jj] * WW * CC;
    f32x4 rs = {0.f, 0.f, 0.f, 0.f};
#pragma unroll
    for (int ii = 0; ii < 4; ++ii) {
      if (xw[ii] != 0.f) {
        f32x4 v = *(const f32x4*)(rp + (size_t)xi[ii] * CC);
        rs += xw[ii] * v;
      }
    }
    val += yw[jj] * rs;
  }
  val *= scale;
  *dst = bf16x4{(__bf16)val.x, (__bf16)val.y, (__bf16)val.z, (__bf16)val.w};
}

// ---------- async 16B global -> LDS ----------
__device__ __forceinline__ void glds16(const void* g, void* l) {
  __builtin_amdgcn_global_load_lds(
      (const __attribute__((address_space(1))) void*)g,
      (__attribute__((address_space(3))) void*)(uint32_t)(uintptr_t)l,
      16, 0, 0);
}

// ---------- K6: GEMM  C[co, r] = sum_k Wbf[co,k] * vox[r,k]; +bias, relu ----------
// M=256 (co), N=32768, K=1280. 128x128 tiles, bf16 MFMA 16x16x32, 4-buffer LDS
// ring, depth-3 glds prefetch, fine-grained vmcnt(8) + raw s_barrier (R5).
// Grid dim3(256,2) NOT (2,256): linear IDs of the two M-halves of N-tile n are
// n and n+256 == same XCD (mod 8) -> vox N-tile L2-shared (R7 showed 1-block/CU
// grid=256 collapses occupancy; this keeps 512 blocks = 2 blocks/CU).
// LDS swizzle: slot (row,c) holds global chunk c ^ ((row>>1)&3). Row stride is
// 64B = 16 banks, so rows equal mod 4 with the same chunk col hit the SAME
// banks; old c ^ (row&3) gave 4-way quarter-wave conflicts (R7: 1.97M
// SQ_LDS_BANK_CONFLICT). f(row)=(row>>1)&3 spreads 16 rows over 8 bank-groups
// x 2 = 2-way = free (m136).
__global__ __launch_bounds__(256) void k6_gemm(const __bf16* __restrict__ A,   // 256 x 1280
                                               const __bf16* __restrict__ Bm,  // 32768 x 1280
                                               const float* __restrict__ bias,
                                               float* __restrict__ out) {
  __shared__ __align__(16) __bf16 As[4][128 * 32];
  __shared__ __align__(16) __bf16 Bs[4][128 * 32];
  const int tileM = blockIdx.y * 128;
  const int tileN = blockIdx.x * 128;
  const int tid = threadIdx.x;
  const int lane = tid & 63;
  const int wave = tid >> 6;
  const int wm = (wave >> 1) * 64;
  const int wn = (wave & 1) * 64;

  f32x4 acc[4][4];
#pragma unroll
  for (int i = 0; i < 4; ++i)
#pragma unroll
    for (int j = 0; j < 4; ++j)
      acc[i][j] = f32x4{0.f, 0.f, 0.f, 0.f};

  const int r16 = lane & 15;
  const int q4 = lane >> 4;        // 0..3 -> k-chunk
  const int srow = (lane >> 2);
  const int sch = lane & 3;

  auto stage = [&](int buf, int kt) {
    const int k0 = kt * 32;
#pragma unroll
    for (int rr = 0; rr < 2; ++rr) {
      const int base_row = wave * 16 + rr * 64;
      const int row = base_row + srow;
      const int gch = sch ^ ((row >> 1) & 3);
      glds16(A  + (size_t)(tileM + row) * KDIM + k0 + gch * 8,
             (void*)(&As[buf][base_row * 32] + lane * 8));
      glds16(Bm + (size_t)(tileN + row) * KDIM + k0 + gch * 8,
             (void*)(&Bs[buf][base_row * 32] + lane * 8));
    }
  };

  stage(0, 0);
  stage(1, 1);
  stage(2, 2);
  for (int kt = 0; kt < NKT; ++kt) {
    const int cur = kt & 3;
    // wait for oldest in-flight stage only: vmcnt(N) = simm16
    // (vmcnt&0xF) | (expcnt<<4) | (lgkmcnt<<8); expcnt=7, lgkmcnt=15 = no-wait.
    if (kt < NKT - 2)       __builtin_amdgcn_s_waitcnt(0xF78);  // vmcnt(8)
    else if (kt == NKT - 2) __builtin_amdgcn_s_waitcnt(0xF74);  // vmcnt(4)
    else                    __builtin_amdgcn_s_waitcnt(0xF70);  // vmcnt(0)
    __builtin_amdgcn_s_barrier();
    if (kt + 3 < NKT) stage((kt + 3) & 3, kt + 3);   // async prefetch, depth 3
    bf16x8 af[4], bg[4];
#pragma unroll
    for (int i = 0; i < 4; ++i) {
      int m = wm + i * 16 + r16;
      af[i] = *(const bf16x8*)(&As[cur][m * 32] + (q4 ^ ((m >> 1) & 3)) * 8);
    }
#pragma unroll
    for (int j = 0; j < 4; ++j) {
      int nr = wn + j * 16 + r16;
      bg[j] = *(const bf16x8*)(&Bs[cur][nr * 32] + (q4 ^ ((nr >> 1) & 3)) * 8);
    }
#pragma unroll
    for (int i = 0; i < 4; ++i)
#pragma unroll
      for (int j = 0; j < 4; ++j)
        acc[i][j] = __builtin_amdgcn_mfma_f32_16x16x32_bf16(af[i], bg[j], acc[i][j], 0, 0, 0);
  }

#pragma unroll
  for (int i = 0; i < 4; ++i) {
#pragma unroll
    for (int j = 0; j < 4; ++j) {
      int nn = tileN + wn + j * 16 + r16;
      int bI = nn >> 14;
      int pix = nn & (NPIX - 1);
#pragma unroll
      for (int r = 0; r < 4; ++r) {
        int co = tileM + wm + i * 16 + q4 * 4 + r;
        float v = acc[i][j][r] + bias[co];
        out[(size_t)(bI * CC + co) * NPIX + pix] = fmaxf(v, 0.f);
      }
    }
  }
}

extern "C" void kernel_launch(void* const* d_in, const int* in_sizes, int n_in,
                              void* d_out, int out_size, void* d_ws, size_t ws_size,
                              hipStream_t stream) {
  const float* feat  = (const float*)d_in[0];
  const float* calib = (const float*)d_in[1];
  const float* grid  = (const float*)d_in[2];
  const float* Wc    = (const float*)d_in[3];
  const float* bc    = (const float*)d_in[4];
  float* out = (float*)d_out;

  char* ws = (char*)d_ws;
  const size_t SZ_INTEG = (size_t)BB * HH * WW * CC * 4;   // 62,914,560
  const size_t SZ_VOX   = (size_t)NDIM * KDIM * 2;         // 83,886,080
  const size_t SZ_WBF   = (size_t)CC * KDIM * 2;           //    655,360
  const size_t SZ_CRD   = (size_t)BB * NLAY * NPIX * 16;   //  2,621,440
  const size_t SZ_SCL   = (size_t)BB * NLAY * NPIX * 4;    //    655,360
  if (ws_size < SZ_INTEG + SZ_VOX + SZ_WBF + SZ_CRD + SZ_SCL) return;

  float*  integ  = (float*)ws;
  __bf16* voxA   = (__bf16*)(ws + SZ_INTEG);
  __bf16* Wbf    = (__bf16*)(ws + SZ_INTEG + SZ_VOX);
  float4* coords = (float4*)(ws + SZ_INTEG + SZ_VOX + SZ_WBF);
  float*  scales = (float*)(ws + SZ_INTEG + SZ_VOX + SZ_WBF + SZ_CRD);

  k1_cumw<<<dim3(BB * HH * 16), dim3(1024), 0, stream>>>(feat, integ);
  k2_cumh<<<dim3(BB * WW * 2), dim3(64), 0, stream>>>(integ);
  k3k5<<<dim3(640 + 1280), dim3(256), 0, stream>>>(grid, calib, Wc, coords, scales, Wbf);
  k4_vox<<<dim3(BB * NLAY * NPIX / 4), dim3(256), 0, stream>>>(integ, coords, scales, voxA);
  k6_gemm<<<dim3(NDIM / 128, 2), dim3(256), 0, stream>>>(Wbf, voxA, bc, out);
}

// Round 9
// 196.565 us; speedup vs baseline: 1.0679x; 1.0270x over previous
//
#include <hip/hip_runtime.h>
#include <hip/hip_bf16.h>
#include <stdint.h>

#define BB 2
#define CC 256
#define HH 96
#define WW 320
#define NPIX 16384
#define NLAY 5
#define KDIM 1280   // CC*NLAY
#define NDIM 32768  // BB*NPIX
#define NKT (KDIM / 32)   // 40 K-tiles

typedef float f32x4 __attribute__((ext_vector_type(4)));
typedef float f32x2 __attribute__((ext_vector_type(2)));
typedef __bf16 bf16x8 __attribute__((ext_vector_type(8)));
typedef __bf16 bf16x4 __attribute__((ext_vector_type(4)));

// ---------- K1: cumsum along W + transpose (B,C,H,W) -> (B,H,W,C) ----------
__global__ __launch_bounds__(1024) void k1_cumw(const float* __restrict__ feat,
                                                float* __restrict__ integ) {
  __shared__ float tile[WW * 17];
  const int t = threadIdx.x;
  const int wave = t >> 6;
  const int lane = t & 63;
  const int blk = blockIdx.x;           // (b, h, cg)
  const int cg = blk & 15;
  const int h = (blk >> 4) % HH;
  const int b = blk / (16 * HH);
  const int c = cg * 16 + wave;
  const float* src = feat + (size_t)((b * CC + c) * HH + h) * WW;

  float carry = 0.f;
#pragma unroll
  for (int chunk = 0; chunk < 5; ++chunk) {
    float v = src[chunk * 64 + lane];
#pragma unroll
    for (int d = 1; d < 64; d <<= 1) {
      float u = __shfl_up(v, d, 64);
      if (lane >= d) v += u;
    }
    v += carry;
    carry = __shfl(v, 63, 64);
    tile[(chunk * 64 + lane) * 17 + wave] = v;
  }
  __syncthreads();
  float* dst = integ + (size_t)((b * HH + h) * WW) * CC + cg * 16;
#pragma unroll
  for (int g = 0; g < 5; ++g) {
    int idx = g * 1024 + t;             // 0..5119
    int w = idx >> 4;
    int cw = idx & 15;
    dst[(size_t)w * CC + cw] = tile[w * 17 + cw];
  }
}

// ---------- K2: cumsum along H, in place on (B,H,W,C) ----------
// Wave per (b, w, c-quarter): lane owns one f32 (256B/instr, coalesced).
// 2560 single-wave blocks = 10 waves/CU: the 96-step column walk is a serial
// dependent chain against L3-resident integ (~300-600 cyc/step); more resident
// chains = more latency overlap (R6's f32x2/5-wave version was ~18us est).
__global__ __launch_bounds__(64) void k2_cumh(float* __restrict__ integ) {
  const int blk = blockIdx.x;            // (b, w, quarter)
  const int q = blk & 3;
  const int w = (blk >> 2) % WW;
  const int b = blk / (4 * WW);
  float* base = integ + ((size_t)(b * HH) * WW + w) * CC + q * 64 + threadIdx.x;
  const size_t stride = (size_t)WW * CC;
  float run = 0.f;
#pragma unroll 8
  for (int h = 0; h < HH; ++h) {
    float* p = base + (size_t)h * stride;
    float v = *p;
    run += v;
    *p = run;
  }
}

// ---------- K3+K5 fused: box geometry (640 blocks) + Wc repack (1280 blocks) --
// NB: keep geometry SEPARATE from k4 — fusing into k4 makes all 64 lanes
// redundantly compute 16 fp32 divides per box (R3: k4 57->173us, VALUBusy 93%).
__global__ __launch_bounds__(256) void k3k5(const float* __restrict__ grid,
                                            const float* __restrict__ calib,
                                            const float* __restrict__ Wc,
                                            float4* __restrict__ coords,
                                            float* __restrict__ scales,
                                            __bf16* __restrict__ Wbf) {
  const int bid = blockIdx.x;
  if (bid >= 640) {                     // ---- K5 part: repack Wc -> bf16 ----
    int o = (bid - 640) * 256 + threadIdx.x;   // co*1280 + n*256 + c
    int co = o / KDIM;
    int kk = o % KDIM;
    int n = kk >> 8;
    int c = kk & 255;
    Wbf[o] = (__bf16)Wc[co * KDIM + c * NLAY + n];
    return;
  }
  // ---- K3 part: one thread per box ----
  int box = bid * 256 + threadIdx.x;    // ((b*5+n)<<14) | pix
  int pix = box & (NPIX - 1);
  int bn = box >> 14;
  int n = bn % NLAY;
  int b = bn / NLAY;
  const float* cb = calib + b * 12;
  float c00 = cb[0], c01 = cb[1], c02 = cb[2], c03 = cb[3];
  float c10 = cb[4], c11 = cb[5], c12 = cb[6], c13 = cb[7];
  float c20 = cb[8], c21 = cb[9], c22 = cb[10], c23 = cb[11];
  float gx = grid[pix * 3 + 0], gy = grid[pix * 3 + 1], gz = grid[pix * 3 + 2];
  float zoff = 32.0f * (float)n;
  const float ox[8] = {-12.5f, 12.5f, 12.5f, -12.5f, -12.5f, 12.5f, 12.5f, -12.5f};
  const float oy[8] = {-12.5f, -12.5f, 12.5f, 12.5f, -12.5f, -12.5f, 12.5f, 12.5f};
  float xmn = 1e30f, ymn = 1e30f, xmx = -1e30f, ymx = -1e30f;
#pragma unroll
  for (int k = 0; k < 8; ++k) {
    float X = gx + ox[k];
    float Y = gy + oy[k];
    float Z = gz + zoff + ((k >= 4) ? 32.0f : 0.0f);
    float px = c00 * X + c01 * Y + c02 * Z + c03;
    float py = c10 * X + c11 * Y + c12 * Z + c13;
    float pz = c20 * X + c21 * Y + c22 * Z + c23;
    float d = fmaxf(pz, 1e-6f);
    float nx = fminf(fmaxf(2.0f * (px / d) / 320.0f - 1.0f, -1.0f), 0.95f);
    float ny = fminf(fmaxf(2.0f * (py / d) / 96.0f - 1.0f, -1.0f), 0.95f);
    xmn = fminf(xmn, nx); xmx = fmaxf(xmx, nx);
    ymn = fminf(ymn, ny); ymx = fmaxf(ymx, ny);
  }
  float dx = xmx - xmn, dy = ymx - ymn;
  float area = (dx * dy) * 30720.0f + 1e-6f;
  bool vis = (area > 1e-6f) && (area < 9216.0f);
  float X0 = ((xmn + 1.0f) * 320.0f - 1.0f) * 0.5f;
  float Y0 = ((ymn + 1.0f) * 96.0f - 1.0f) * 0.5f;
  float X1 = ((xmx + 1.0f) * 320.0f - 1.0f) * 0.5f;
  float Y1 = ((ymx + 1.0f) * 96.0f - 1.0f) * 0.5f;
  coords[box] = make_float4(X0, Y0, X1, Y1);
  scales[box] = vis ? 1.0f / area : 0.0f;
}

// ---------- K4: box-filtered features -> vox (bf16), K permuted to n*256+c ----------
// FOUR boxes per wave (R9): 4 independent scale/coord/tap load streams
// interleave -> 4-deep memory ILP per wave, 4x fewer wave launch/drains
// (163840 -> 40960 waves). Lane owns 4 contiguous channels -> float4 taps.
__global__ __launch_bounds__(256) void k4_vox(const float* __restrict__ integ,
                                              const float4* __restrict__ coords,
                                              const float* __restrict__ scales,
                                              __bf16* __restrict__ voxA) {
  const int wave = threadIdx.x >> 6;
  const int lane = threadIdx.x & 63;
  const int box0 = (blockIdx.x * 4 + wave) * 4;
#pragma unroll
  for (int u = 0; u < 4; ++u) {
    const int box = box0 + u;
    const int pix = box & (NPIX - 1);
    const int bn = box >> 14;
    const int n = bn % NLAY;
    const int b = bn / NLAY;
    const size_t row = (size_t)(b * NPIX + pix);
    bf16x4* dst = (bf16x4*)(voxA + row * KDIM + n * CC + lane * 4);
    const float scale = scales[box];
    if (scale == 0.f) {                 // wave-uniform branch
      *dst = bf16x4{(__bf16)0.f, (__bf16)0.f, (__bf16)0.f, (__bf16)0.f};
      continue;
    }
    const float4 q = coords[box];

    float xw[4]; int xi[4];
    float yw[4]; int yi[4];
    {
      float f0 = floorf(q.x); int i0 = (int)f0; float w1 = q.x - f0;
      xw[0] = (i0 >= 0 && i0 < WW) ? (1.f - w1) : 0.f;
      xw[1] = (i0 + 1 < WW) ? w1 : 0.f;
      xi[0] = min(max(i0, 0), WW - 1); xi[1] = min(max(i0 + 1, 0), WW - 1);
      float f1 = floorf(q.z); int i1 = (int)f1; float v1 = q.z - f1;
      xw[2] = (i1 >= 0 && i1 < WW) ? -(1.f - v1) : 0.f;
      xw[3] = (i1 + 1 < WW) ? -v1 : 0.f;
      xi[2] = min(max(i1, 0), WW - 1); xi[3] = min(max(i1 + 1, 0), WW - 1);
    }
    {
      float f0 = floorf(q.y); int j0 = (int)f0; float w1 = q.y - f0;
      yw[0] = (j0 >= 0 && j0 < HH) ? (1.f - w1) : 0.f;
      yw[1] = (j0 + 1 < HH) ? w1 : 0.f;
      yi[0] = min(max(j0, 0), HH - 1); yi[1] = min(max(j0 + 1, 0), HH - 1);
      float f1 = floorf(q.w); int j1 = (int)f1; float v1 = q.w - f1;
      yw[2] = (j1 >= 0 && j1 < HH) ? -(1.f - v1) : 0.f;
      yw[3] = (j1 + 1 < HH) ? -v1 : 0.f;
      yi[2] = min(max(j1, 0), HH - 1); yi[3] = min(max(j1 + 1, 0), HH - 1);
    }
    const float* base = integ + (size_t)(b * HH) * WW * CC + lane * 4;
    f32x4 val = {0.f, 0.f, 0.f, 0.f};
#pragma unroll
    for (int jj = 0; jj < 4; ++jj) {
      if (yw[jj] == 0.f) continue;          // wave-uniform branch
      const float* rp = base + (size_t)yi[jj] * WW * CC;
      f32x4 rs = {0.f, 0.f, 0.f, 0.f};
#pragma unroll
      for (int ii = 0; ii < 4; ++ii) {
        if (xw[ii] != 0.f) {
          f32x4 v = *(const f32x4*)(rp + (size_t)xi[ii] * CC);
          rs += xw[ii] * v;
        }
      }
      val += yw[jj] * rs;
    }
    val *= scale;
    *dst = bf16x4{(__bf16)val.x, (__bf16)val.y, (__bf16)val.z, (__bf16)val.w};
  }
}

// ---------- async 16B global -> LDS ----------
__device__ __forceinline__ void glds16(const void* g, void* l) {
  __builtin_amdgcn_global_load_lds(
      (const __attribute__((address_space(1))) void*)g,
      (__attribute__((address_space(3))) void*)(uint32_t)(uintptr_t)l,
      16, 0, 0);
}

// ---------- K6: GEMM  C[co, r] = sum_k Wbf[co,k] * vox[r,k]; +bias, relu ----------
// M=256 (co), N=32768, K=1280. 128x128 tiles, bf16 MFMA 16x16x32, 4-buffer LDS
// ring, depth-3 glds prefetch, fine-grained vmcnt(8) + raw s_barrier.
// Ring-4/depth-3 is the ONLY single-barrier-safe shape: stage kt+3's target
// buffer's last readers (iter kt-1) consumed their frags (MFMA lgkm waits)
// before barrier kt. 2-buffer variants race sibling waves' ds_reads (R9 note).
// Grid dim3(256,2): the two M-halves of N-tile n get linear IDs n and n+256 ==
// same XCD (mod 8) -> vox N-tile L2-shared; 512 blocks = 2 blocks/CU.
// LDS swizzle: slot (row,c) holds global chunk c ^ ((row>>1)&3) -> quarter-wave
// frag reads spread 2-way over banks (free); c ^ (row&3) was 4-way (R7: 1.97M
// SQ_LDS_BANK_CONFLICT).
__global__ __launch_bounds__(256) void k6_gemm(const __bf16* __restrict__ A,   // 256 x 1280
                                               const __bf16* __restrict__ Bm,  // 32768 x 1280
                                               const float* __restrict__ bias,
                                               float* __restrict__ out) {
  __shared__ __align__(16) __bf16 As[4][128 * 32];
  __shared__ __align__(16) __bf16 Bs[4][128 * 32];
  const int tileM = blockIdx.y * 128;
  const int tileN = blockIdx.x * 128;
  const int tid = threadIdx.x;
  const int lane = tid & 63;
  const int wave = tid >> 6;
  const int wm = (wave >> 1) * 64;
  const int wn = (wave & 1) * 64;

  f32x4 acc[4][4];
#pragma unroll
  for (int i = 0; i < 4; ++i)
#pragma unroll
    for (int j = 0; j < 4; ++j)
      acc[i][j] = f32x4{0.f, 0.f, 0.f, 0.f};

  const int r16 = lane & 15;
  const int q4 = lane >> 4;        // 0..3 -> k-chunk
  const int srow = (lane >> 2);
  const int sch = lane & 3;

  auto stage = [&](int buf, int kt) {
    const int k0 = kt * 32;
#pragma unroll
    for (int rr = 0; rr < 2; ++rr) {
      const int base_row = wave * 16 + rr * 64;
      const int row = base_row + srow;
      const int gch = sch ^ ((row >> 1) & 3);
      glds16(A  + (size_t)(tileM + row) * KDIM + k0 + gch * 8,
             (void*)(&As[buf][base_row * 32] + lane * 8));
      glds16(Bm + (size_t)(tileN + row) * KDIM + k0 + gch * 8,
             (void*)(&Bs[buf][base_row * 32] + lane * 8));
    }
  };

  stage(0, 0);
  stage(1, 1);
  stage(2, 2);
  for (int kt = 0; kt < NKT; ++kt) {
    const int cur = kt & 3;
    // wait for oldest in-flight stage only: vmcnt(N) = simm16
    // (vmcnt&0xF) | (expcnt<<4) | (lgkmcnt<<8); expcnt=7, lgkmcnt=15 = no-wait.
    if (kt < NKT - 2)       __builtin_amdgcn_s_waitcnt(0xF78);  // vmcnt(8)
    else if (kt == NKT - 2) __builtin_amdgcn_s_waitcnt(0xF74);  // vmcnt(4)
    else                    __builtin_amdgcn_s_waitcnt(0xF70);  // vmcnt(0)
    __builtin_amdgcn_s_barrier();
    if (kt + 3 < NKT) stage((kt + 3) & 3, kt + 3);   // async prefetch, depth 3
    bf16x8 af[4], bg[4];
#pragma unroll
    for (int i = 0; i < 4; ++i) {
      int m = wm + i * 16 + r16;
      af[i] = *(const bf16x8*)(&As[cur][m * 32] + (q4 ^ ((m >> 1) & 3)) * 8);
    }
#pragma unroll
    for (int j = 0; j < 4; ++j) {
      int nr = wn + j * 16 + r16;
      bg[j] = *(const bf16x8*)(&Bs[cur][nr * 32] + (q4 ^ ((nr >> 1) & 3)) * 8);
    }
#pragma unroll
    for (int i = 0; i < 4; ++i)
#pragma unroll
      for (int j = 0; j < 4; ++j)
        acc[i][j] = __builtin_amdgcn_mfma_f32_16x16x32_bf16(af[i], bg[j], acc[i][j], 0, 0, 0);
  }

#pragma unroll
  for (int i = 0; i < 4; ++i) {
#pragma unroll
    for (int j = 0; j < 4; ++j) {
      int nn = tileN + wn + j * 16 + r16;
      int bI = nn >> 14;
      int pix = nn & (NPIX - 1);
#pragma unroll
      for (int r = 0; r < 4; ++r) {
        int co = tileM + wm + i * 16 + q4 * 4 + r;
        float v = acc[i][j][r] + bias[co];
        out[(size_t)(bI * CC + co) * NPIX + pix] = fmaxf(v, 0.f);
      }
    }
  }
}

extern "C" void kernel_launch(void* const* d_in, const int* in_sizes, int n_in,
                              void* d_out, int out_size, void* d_ws, size_t ws_size,
                              hipStream_t stream) {
  const float* feat  = (const float*)d_in[0];
  const float* calib = (const float*)d_in[1];
  const float* grid  = (const float*)d_in[2];
  const float* Wc    = (const float*)d_in[3];
  const float* bc    = (const float*)d_in[4];
  float* out = (float*)d_out;

  char* ws = (char*)d_ws;
  const size_t SZ_INTEG = (size_t)BB * HH * WW * CC * 4;   // 62,914,560
  const size_t SZ_VOX   = (size_t)NDIM * KDIM * 2;         // 83,886,080
  const size_t SZ_WBF   = (size_t)CC * KDIM * 2;           //    655,360
  const size_t SZ_CRD   = (size_t)BB * NLAY * NPIX * 16;   //  2,621,440
  const size_t SZ_SCL   = (size_t)BB * NLAY * NPIX * 4;    //    655,360
  if (ws_size < SZ_INTEG + SZ_VOX + SZ_WBF + SZ_CRD + SZ_SCL) return;

  float*  integ  = (float*)ws;
  __bf16* voxA   = (__bf16*)(ws + SZ_INTEG);
  __bf16* Wbf    = (__bf16*)(ws + SZ_INTEG + SZ_VOX);
  float4* coords = (float4*)(ws + SZ_INTEG + SZ_VOX + SZ_WBF);
  float*  scales = (float*)(ws + SZ_INTEG + SZ_VOX + SZ_WBF + SZ_CRD);

  k1_cumw<<<dim3(BB * HH * 16), dim3(1024), 0, stream>>>(feat, integ);
  k2_cumh<<<dim3(BB * WW * 4), dim3(64), 0, stream>>>(integ);
  k3k5<<<dim3(640 + 1280), dim3(256), 0, stream>>>(grid, calib, Wc, coords, scales, Wbf);
  k4_vox<<<dim3(BB * NLAY * NPIX / 16), dim3(256), 0, stream>>>(integ, coords, scales, voxA);
  k6_gemm<<<dim3(NDIM / 128, 2), dim3(256), 0, stream>>>(Wbf, voxA, bc, out);
}

// Round 10
// 194.220 us; speedup vs baseline: 1.0808x; 1.0121x over previous
//
#include <hip/hip_runtime.h>
#include <hip/hip_bf16.h>
#include <stdint.h>

#define BB 2
#define CC 256
#define HH 96
#define WW 320
#define NPIX 16384
#define NLAY 5
#define KDIM 1280   // CC*NLAY
#define NDIM 32768  // BB*NPIX
#define NKT (KDIM / 32)   // 40 K-tiles

typedef float f32x4 __attribute__((ext_vector_type(4)));
typedef float f32x2 __attribute__((ext_vector_type(2)));
typedef __bf16 bf16x8 __attribute__((ext_vector_type(8)));
typedef __bf16 bf16x4 __attribute__((ext_vector_type(4)));

// ---------- K1 (+K3+K5 fused as extra blocks): ----------
// blocks [0,3072): cumsum along W + transpose (B,C,H,W) -> (B,H,W,C).
// blocks [3072,3552): box geometry + Wc repack (1920 old 256-thread blocks
// repacked 4-per-1024-block). Branch is block-uniform -> k1's __syncthreads
// is only reached by k1 blocks (safe).
__global__ __launch_bounds__(1024) void k1f(const float* __restrict__ feat,
                                            float* __restrict__ integ,
                                            const float* __restrict__ gridp,
                                            const float* __restrict__ calib,
                                            const float* __restrict__ Wc,
                                            float4* __restrict__ coords,
                                            float* __restrict__ scales,
                                            __bf16* __restrict__ Wbf) {
  const int bid = blockIdx.x;
  if (bid >= BB * HH * 16) {
    // ---- K3/K5 part ----
    const int vbid = (bid - BB * HH * 16) * 4 + (threadIdx.x >> 8);
    const int vt = threadIdx.x & 255;
    if (vbid >= 640) {                  // K5: repack Wc (co, c*5+n) -> bf16 (co, n*256+c)
      int o = (vbid - 640) * 256 + vt;
      int co = o / KDIM;
      int kk = o % KDIM;
      int n = kk >> 8;
      int c = kk & 255;
      Wbf[o] = (__bf16)Wc[co * KDIM + c * NLAY + n];
      return;
    }
    // K3: one thread per box. Keep SEPARATE from k4 — fusing into k4 makes all
    // 64 lanes redundantly compute 16 fp32 divides (R3: k4 57->173us).
    int box = vbid * 256 + vt;          // ((b*5+n)<<14) | pix
    int pix = box & (NPIX - 1);
    int bn = box >> 14;
    int n = bn % NLAY;
    int b = bn / NLAY;
    const float* cb = calib + b * 12;
    float c00 = cb[0], c01 = cb[1], c02 = cb[2], c03 = cb[3];
    float c10 = cb[4], c11 = cb[5], c12 = cb[6], c13 = cb[7];
    float c20 = cb[8], c21 = cb[9], c22 = cb[10], c23 = cb[11];
    float gx = gridp[pix * 3 + 0], gy = gridp[pix * 3 + 1], gz = gridp[pix * 3 + 2];
    float zoff = 32.0f * (float)n;
    const float ox[8] = {-12.5f, 12.5f, 12.5f, -12.5f, -12.5f, 12.5f, 12.5f, -12.5f};
    const float oy[8] = {-12.5f, -12.5f, 12.5f, 12.5f, -12.5f, -12.5f, 12.5f, 12.5f};
    float xmn = 1e30f, ymn = 1e30f, xmx = -1e30f, ymx = -1e30f;
#pragma unroll
    for (int k = 0; k < 8; ++k) {
      float X = gx + ox[k];
      float Y = gy + oy[k];
      float Z = gz + zoff + ((k >= 4) ? 32.0f : 0.0f);
      float px = c00 * X + c01 * Y + c02 * Z + c03;
      float py = c10 * X + c11 * Y + c12 * Z + c13;
      float pz = c20 * X + c21 * Y + c22 * Z + c23;
      float d = fmaxf(pz, 1e-6f);
      float nx = fminf(fmaxf(2.0f * (px / d) / 320.0f - 1.0f, -1.0f), 0.95f);
      float ny = fminf(fmaxf(2.0f * (py / d) / 96.0f - 1.0f, -1.0f), 0.95f);
      xmn = fminf(xmn, nx); xmx = fmaxf(xmx, nx);
      ymn = fminf(ymn, ny); ymx = fmaxf(ymx, ny);
    }
    float dx = xmx - xmn, dy = ymx - ymn;
    float area = (dx * dy) * 30720.0f + 1e-6f;
    bool vis = (area > 1e-6f) && (area < 9216.0f);
    float X0 = ((xmn + 1.0f) * 320.0f - 1.0f) * 0.5f;
    float Y0 = ((ymn + 1.0f) * 96.0f - 1.0f) * 0.5f;
    float X1 = ((xmx + 1.0f) * 320.0f - 1.0f) * 0.5f;
    float Y1 = ((ymx + 1.0f) * 96.0f - 1.0f) * 0.5f;
    coords[box] = make_float4(X0, Y0, X1, Y1);
    scales[box] = vis ? 1.0f / area : 0.0f;
    return;
  }
  // ---- K1 part: wave-parallel W-scan, one wave per (b,h,c) row ----
  __shared__ float tile[WW * 17];
  const int t = threadIdx.x;
  const int wave = t >> 6;
  const int lane = t & 63;
  const int cg = bid & 15;
  const int h = (bid >> 4) % HH;
  const int b = bid / (16 * HH);
  const int c = cg * 16 + wave;
  const float* src = feat + (size_t)((b * CC + c) * HH + h) * WW;

  float carry = 0.f;
#pragma unroll
  for (int chunk = 0; chunk < 5; ++chunk) {
    float v = src[chunk * 64 + lane];
#pragma unroll
    for (int d = 1; d < 64; d <<= 1) {
      float u = __shfl_up(v, d, 64);
      if (lane >= d) v += u;
    }
    v += carry;
    carry = __shfl(v, 63, 64);
    tile[(chunk * 64 + lane) * 17 + wave] = v;
  }
  __syncthreads();
  float* dst = integ + (size_t)((b * HH + h) * WW) * CC + cg * 16;
#pragma unroll
  for (int g = 0; g < 5; ++g) {
    int idx = g * 1024 + t;             // 0..5119
    int w = idx >> 4;
    int cw = idx & 15;
    dst[(size_t)w * CC + cw] = tile[w * 17 + cw];
  }
}

// ---------- K2: cumsum along H, in place on (B,H,W,C) ----------
// Two-level scan, NO serial global chain (old version: 96 dependent
// read-modify-writes at ~L3 latency each). Thread (g,l) owns channel c=cq*64+l
// and h-range [g*24, g*24+24): 24 INDEPENDENT 256B-coalesced loads (deep ILP),
// in-register inclusive scan, 4 partials exchanged via LDS, offset added,
// 24 coalesced stores. Element traffic identical (read once, write once).
// Grid 2560 x 256 = 40 waves/CU.
__global__ __launch_bounds__(256) void k2_scan(float* __restrict__ integ) {
  const int blk = blockIdx.x;            // (b, w, cq)
  const int cq = blk & 3;
  const int w = (blk >> 2) % WW;
  const int b = blk / (4 * WW);
  const int g = threadIdx.x >> 6;        // 0..3 h-group
  const int l = threadIdx.x & 63;
  float* base = integ + ((size_t)(b * HH + g * 24) * WW + w) * CC + cq * 64 + l;
  const size_t stride = (size_t)WW * CC;
  float v[24];
#pragma unroll
  for (int i = 0; i < 24; ++i) v[i] = base[(size_t)i * stride];
#pragma unroll
  for (int i = 1; i < 24; ++i) v[i] += v[i - 1];
  __shared__ float part[4][64];
  part[g][l] = v[23];
  __syncthreads();
  float off = 0.f;
#pragma unroll
  for (int gg = 0; gg < 3; ++gg)
    if (gg < g) off += part[gg][l];
#pragma unroll
  for (int i = 0; i < 24; ++i) base[(size_t)i * stride] = v[i] + off;
}

// ---------- K4: box-filtered features -> vox (bf16), K permuted to n*256+c ----------
// FOUR boxes per wave: 4 independent scale/coord/tap load streams interleave
// -> 4-deep memory ILP, 4x fewer wave drains. Lane owns 4 contiguous channels.
__global__ __launch_bounds__(256) void k4_vox(const float* __restrict__ integ,
                                              const float4* __restrict__ coords,
                                              const float* __restrict__ scales,
                                              __bf16* __restrict__ voxA) {
  const int wave = threadIdx.x >> 6;
  const int lane = threadIdx.x & 63;
  const int box0 = (blockIdx.x * 4 + wave) * 4;
#pragma unroll
  for (int u = 0; u < 4; ++u) {
    const int box = box0 + u;
    const int pix = box & (NPIX - 1);
    const int bn = box >> 14;
    const int n = bn % NLAY;
    const int b = bn / NLAY;
    const size_t row = (size_t)(b * NPIX + pix);
    bf16x4* dst = (bf16x4*)(voxA + row * KDIM + n * CC + lane * 4);
    const float scale = scales[box];
    if (scale == 0.f) {                 // wave-uniform branch
      *dst = bf16x4{(__bf16)0.f, (__bf16)0.f, (__bf16)0.f, (__bf16)0.f};
      continue;
    }
    const float4 q = coords[box];

    float xw[4]; int xi[4];
    float yw[4]; int yi[4];
    {
      float f0 = floorf(q.x); int i0 = (int)f0; float w1 = q.x - f0;
      xw[0] = (i0 >= 0 && i0 < WW) ? (1.f - w1) : 0.f;
      xw[1] = (i0 + 1 < WW) ? w1 : 0.f;
      xi[0] = min(max(i0, 0), WW - 1); xi[1] = min(max(i0 + 1, 0), WW - 1);
      float f1 = floorf(q.z); int i1 = (int)f1; float v1 = q.z - f1;
      xw[2] = (i1 >= 0 && i1 < WW) ? -(1.f - v1) : 0.f;
      xw[3] = (i1 + 1 < WW) ? -v1 : 0.f;
      xi[2] = min(max(i1, 0), WW - 1); xi[3] = min(max(i1 + 1, 0), WW - 1);
    }
    {
      float f0 = floorf(q.y); int j0 = (int)f0; float w1 = q.y - f0;
      yw[0] = (j0 >= 0 && j0 < HH) ? (1.f - w1) : 0.f;
      yw[1] = (j0 + 1 < HH) ? w1 : 0.f;
      yi[0] = min(max(j0, 0), HH - 1); yi[1] = min(max(j0 + 1, 0), HH - 1);
      float f1 = floorf(q.w); int j1 = (int)f1; float v1 = q.w - f1;
      yw[2] = (j1 >= 0 && j1 < HH) ? -(1.f - v1) : 0.f;
      yw[3] = (j1 + 1 < HH) ? -v1 : 0.f;
      yi[2] = min(max(j1, 0), HH - 1); yi[3] = min(max(j1 + 1, 0), HH - 1);
    }
    const float* base = integ + (size_t)(b * HH) * WW * CC + lane * 4;
    f32x4 val = {0.f, 0.f, 0.f, 0.f};
#pragma unroll
    for (int jj = 0; jj < 4; ++jj) {
      if (yw[jj] == 0.f) continue;          // wave-uniform branch
      const float* rp = base + (size_t)yi[jj] * WW * CC;
      f32x4 rs = {0.f, 0.f, 0.f, 0.f};
#pragma unroll
      for (int ii = 0; ii < 4; ++ii) {
        if (xw[ii] != 0.f) {
          f32x4 v = *(const f32x4*)(rp + (size_t)xi[ii] * CC);
          rs += xw[ii] * v;
        }
      }
      val += yw[jj] * rs;
    }
    val *= scale;
    *dst = bf16x4{(__bf16)val.x, (__bf16)val.y, (__bf16)val.z, (__bf16)val.w};
  }
}

// ---------- async 16B global -> LDS ----------
__device__ __forceinline__ void glds16(const void* g, void* l) {
  __builtin_amdgcn_global_load_lds(
      (const __attribute__((address_space(1))) void*)g,
      (__attribute__((address_space(3))) void*)(uint32_t)(uintptr_t)l,
      16, 0, 0);
}

// ---------- K6: GEMM  C[co, r] = sum_k Wbf[co,k] * vox[r,k]; +bias, relu ----------
// M=256 (co), N=32768, K=1280. 128x128 tiles, bf16 MFMA 16x16x32, 4-buffer LDS
// ring, depth-3 glds prefetch, fine-grained vmcnt(8) + raw s_barrier.
// Ring-4/depth-3 is the ONLY single-barrier-safe shape: stage kt+3's target
// buffer's last readers (iter kt-1) consumed their frags before barrier kt.
// Grid dim3(256,2): the two M-halves of N-tile n get linear IDs n and n+256 ==
// same XCD (mod 8) -> vox N-tile L2-shared; 512 blocks = 2 blocks/CU.
// LDS swizzle: slot (row,c) holds global chunk c ^ ((row>>1)&3) -> quarter-wave
// frag reads spread 2-way over banks (free); c ^ (row&3) was 4-way (R7: 1.97M
// SQ_LDS_BANK_CONFLICT).
__global__ __launch_bounds__(256) void k6_gemm(const __bf16* __restrict__ A,   // 256 x 1280
                                               const __bf16* __restrict__ Bm,  // 32768 x 1280
                                               const float* __restrict__ bias,
                                               float* __restrict__ out) {
  __shared__ __align__(16) __bf16 As[4][128 * 32];
  __shared__ __align__(16) __bf16 Bs[4][128 * 32];
  const int tileM = blockIdx.y * 128;
  const int tileN = blockIdx.x * 128;
  const int tid = threadIdx.x;
  const int lane = tid & 63;
  const int wave = tid >> 6;
  const int wm = (wave >> 1) * 64;
  const int wn = (wave & 1) * 64;

  f32x4 acc[4][4];
#pragma unroll
  for (int i = 0; i < 4; ++i)
#pragma unroll
    for (int j = 0; j < 4; ++j)
      acc[i][j] = f32x4{0.f, 0.f, 0.f, 0.f};

  const int r16 = lane & 15;
  const int q4 = lane >> 4;        // 0..3 -> k-chunk
  const int srow = (lane >> 2);
  const int sch = lane & 3;

  auto stage = [&](int buf, int kt) {
    const int k0 = kt * 32;
#pragma unroll
    for (int rr = 0; rr < 2; ++rr) {
      const int base_row = wave * 16 + rr * 64;
      const int row = base_row + srow;
      const int gch = sch ^ ((row >> 1) & 3);
      glds16(A  + (size_t)(tileM + row) * KDIM + k0 + gch * 8,
             (void*)(&As[buf][base_row * 32] + lane * 8));
      glds16(Bm + (size_t)(tileN + row) * KDIM + k0 + gch * 8,
             (void*)(&Bs[buf][base_row * 32] + lane * 8));
    }
  };

  stage(0, 0);
  stage(1, 1);
  stage(2, 2);
  for (int kt = 0; kt < NKT; ++kt) {
    const int cur = kt & 3;
    // wait for oldest in-flight stage only: vmcnt(N) = simm16
    // (vmcnt&0xF) | (expcnt<<4) | (lgkmcnt<<8); expcnt=7, lgkmcnt=15 = no-wait.
    if (kt < NKT - 2)       __builtin_amdgcn_s_waitcnt(0xF78);  // vmcnt(8)
    else if (kt == NKT - 2) __builtin_amdgcn_s_waitcnt(0xF74);  // vmcnt(4)
    else                    __builtin_amdgcn_s_waitcnt(0xF70);  // vmcnt(0)
    __builtin_amdgcn_s_barrier();
    if (kt + 3 < NKT) stage((kt + 3) & 3, kt + 3);   // async prefetch, depth 3
    bf16x8 af[4], bg[4];
#pragma unroll
    for (int i = 0; i < 4; ++i) {
      int m = wm + i * 16 + r16;
      af[i] = *(const bf16x8*)(&As[cur][m * 32] + (q4 ^ ((m >> 1) & 3)) * 8);
    }
#pragma unroll
    for (int j = 0; j < 4; ++j) {
      int nr = wn + j * 16 + r16;
      bg[j] = *(const bf16x8*)(&Bs[cur][nr * 32] + (q4 ^ ((nr >> 1) & 3)) * 8);
    }
#pragma unroll
    for (int i = 0; i < 4; ++i)
#pragma unroll
      for (int j = 0; j < 4; ++j)
        acc[i][j] = __builtin_amdgcn_mfma_f32_16x16x32_bf16(af[i], bg[j], acc[i][j], 0, 0, 0);
  }

#pragma unroll
  for (int i = 0; i < 4; ++i) {
#pragma unroll
    for (int j = 0; j < 4; ++j) {
      int nn = tileN + wn + j * 16 + r16;
      int bI = nn >> 14;
      int pix = nn & (NPIX - 1);
#pragma unroll
      for (int r = 0; r < 4; ++r) {
        int co = tileM + wm + i * 16 + q4 * 4 + r;
        float v = acc[i][j][r] + bias[co];
        out[(size_t)(bI * CC + co) * NPIX + pix] = fmaxf(v, 0.f);
      }
    }
  }
}

extern "C" void kernel_launch(void* const* d_in, const int* in_sizes, int n_in,
                              void* d_out, int out_size, void* d_ws, size_t ws_size,
                              hipStream_t stream) {
  const float* feat  = (const float*)d_in[0];
  const float* calib = (const float*)d_in[1];
  const float* grid  = (const float*)d_in[2];
  const float* Wc    = (const float*)d_in[3];
  const float* bc    = (const float*)d_in[4];
  float* out = (float*)d_out;

  char* ws = (char*)d_ws;
  const size_t SZ_INTEG = (size_t)BB * HH * WW * CC * 4;   // 62,914,560
  const size_t SZ_VOX   = (size_t)NDIM * KDIM * 2;         // 83,886,080
  const size_t SZ_WBF   = (size_t)CC * KDIM * 2;           //    655,360
  const size_t SZ_CRD   = (size_t)BB * NLAY * NPIX * 16;   //  2,621,440
  const size_t SZ_SCL   = (size_t)BB * NLAY * NPIX * 4;    //    655,360
  if (ws_size < SZ_INTEG + SZ_VOX + SZ_WBF + SZ_CRD + SZ_SCL) return;

  float*  integ  = (float*)ws;
  __bf16* voxA   = (__bf16*)(ws + SZ_INTEG);
  __bf16* Wbf    = (__bf16*)(ws + SZ_INTEG + SZ_VOX);
  float4* coords = (float4*)(ws + SZ_INTEG + SZ_VOX + SZ_WBF);
  float*  scales = (float*)(ws + SZ_INTEG + SZ_VOX + SZ_WBF + SZ_CRD);

  k1f<<<dim3(BB * HH * 16 + 480), dim3(1024), 0, stream>>>(
      feat, integ, grid, calib, Wc, coords, scales, Wbf);
  k2_scan<<<dim3(BB * WW * 4), dim3(256), 0, stream>>>(integ);
  k4_vox<<<dim3(BB * NLAY * NPIX / 16), dim3(256), 0, stream>>>(integ, coords, scales, voxA);
  k6_gemm<<<dim3(NDIM / 128, 2), dim3(256), 0, stream>>>(Wbf, voxA, bc, out);
}